// Round 7
// baseline (102.692 us; speedup 1.0000x reference)
//
#include <hip/hip_runtime.h>
#include <hip/hip_bf16.h>
#include <cstdint>
#include <cstddef>

#define M_DIM 4096
#define N_DIM 4096
#define K_DIM 4096
#define NT    (K_DIM / 128)   // 32 K-tiles of BK=128

using i32x4  = __attribute__((ext_vector_type(4))) int;
using s8x16  = __attribute__((ext_vector_type(16))) char;
using float4v = __attribute__((ext_vector_type(4))) float;

__device__ __forceinline__ void gload_lds16(const void* g, void* l) {
    __builtin_amdgcn_global_load_lds(
        (const __attribute__((address_space(1))) uint32_t*)g,
        (__attribute__((address_space(3))) uint32_t*)l, 16, 0, 0);
}

__device__ __forceinline__ i32x4 mfma_i8(i32x4 a, i32x4 b, i32x4 c) {
    return __builtin_amdgcn_mfma_i32_16x16x64_i8(a, b, c, 0, 0, 0);
}

// ------------- pass 1a: x (f32) -> i8  q = clamp(rint(32x), ±127) -------------
__global__ __launch_bounds__(256) void cvt_x_kernel(const float* __restrict__ x,
                                                    char* __restrict__ xq,
                                                    int n16) {
    int idx = blockIdx.x * blockDim.x + threadIdx.x;
    int stride = gridDim.x * blockDim.x;
    for (int i = idx; i < n16; i += stride) {
        const float4v* p = (const float4v*)(x + (size_t)i * 16);
        s8x16 o;
#pragma unroll
        for (int v = 0; v < 4; ++v) {
            float4v f = p[v];
#pragma unroll
            for (int j = 0; j < 4; ++j) {
                float q = __builtin_rintf(f[j] * 32.0f);
                q = fminf(127.0f, fmaxf(-127.0f, q));
                o[v * 4 + j] = (char)(int)q;
            }
        }
        *(s8x16*)(xq + (size_t)i * 16) = o;
    }
}

// ------ pass 1b: W (K x N, f32) -> sign -> i8, TRANSPOSED to N x K ------
__global__ __launch_bounds__(256) void sign_wt_kernel(const float* __restrict__ W,
                                                      char* __restrict__ WqT) {
    __shared__ char tile[64][68];
    int j0 = blockIdx.x * 64;
    int k0 = blockIdx.y * 64;
    int tx = threadIdx.x;
    int ty = threadIdx.y;
#pragma unroll
    for (int i = 0; i < 16; ++i) {
        int kk = ty + i * 4;
        float w = W[(size_t)(k0 + kk) * N_DIM + (j0 + tx)];
        tile[kk][tx] = (char)((w > 0.f) - (w < 0.f));
    }
    __syncthreads();
#pragma unroll
    for (int i = 0; i < 16; ++i) {
        int jj = ty + i * 4;
        WqT[(size_t)(j0 + jj) * K_DIM + (k0 + tx)] = tile[tx][jj];
    }
}

// ---------------- pass 2: 256x256-tile i8 MFMA GEMM, BK=128 ----------------
// Software-pipelined 8-phase schedule, 8 MFMA per phase, all reads issued >=1
// phase before their consuming MFMA group, using ONLY the freed register banks
// (no extra VGPR vs R5). 4 barriers/tile; stage-over-read hazards are
// consumption-enforced (last read of a region is consumed by an MFMA group
// before the guarding barrier).
//
// Quad/group order per tile: G1=Q00k0 G2=Q00k1 G3=Q01k0 G4=Q01k1
//                            G5=Q11k0 G6=Q11k1 G7=Q10k0 G8=Q10k1
// Bank lifetimes: aF[*][0]: mh0k0 (G1,G3) -> overwritten ph3 with mh1k0 (G5,G7)
//                 aF[*][1]: mh0k1 (G2,G4) -> overwritten ph4 with mh1k1 (G6,G8)
//                 bL: nh0 (G1,G2,G7,G8)   bH: nh1 (G3,G4,G5,G6)
// Stage ledger: A-mh0 (blk0,2) last read ph0, consumed G2(ph1) -> stage ph2
//               B (blk0-3)     last read ph2, consumed G4(ph3) -> stage ph4
//               A-mh1 (blk1,3) last read ph4, consumed G6(ph5) -> stage ph6
// vmcnt(8) at ph7-start: kt+1's 8 stages landed, kt+2's 8 in flight.

#define STAGE_A(p, b, kt)                                                        \
    gload_lds16(AbaseG + (size_t)((b) * 64) * K_DIM + (size_t)(kt) * 128,        \
                lds + (p) * 32768 + (b) * 8192 + (t << 4))
#define STAGE_B(p, b, kt)                                                        \
    gload_lds16(BbaseG + (size_t)((b) * 64) * K_DIM + (size_t)(kt) * 128,        \
                lds + 65536 + (p) * 32768 + (b) * 8192 + (t << 4))

#define RD_A(p, mh, mq, kk)                                                      \
    (*(const i32x4*)(ldsc + (p) * 32768 + aB + (mh) * 8192 + (mq) * 2048 +       \
                     (kk) * 1024))
#define RD_B(p, nh, nq, kk)                                                      \
    (*(const i32x4*)(ldsc + 65536 + (p) * 32768 + bB + (nh) * 4096 +             \
                     (nq) * 2048 + (kk) * 1024))

#define MFMA_G(MH, NH, KK, Barr) do {                                            \
    __builtin_amdgcn_s_setprio(1);                                               \
    _Pragma("unroll")                                                            \
    for (int mq = 0; mq < 4; ++mq)                                               \
        _Pragma("unroll")                                                        \
        for (int nq = 0; nq < 2; ++nq)                                           \
            acc[(MH) * 4 + mq][(NH) * 2 + nq] =                                  \
                mfma_i8(aF[mq][KK], Barr[nq][KK],                                \
                        acc[(MH) * 4 + mq][(NH) * 2 + nq]);                      \
    __builtin_amdgcn_s_setprio(0);                                               \
} while (0)

#define SCHED0 __builtin_amdgcn_sched_barrier(0)

#define TILE8(kt, p) do {                                                        \
    /* ph0: read aF0k1(4) + bLk1(2) [for G2]; G1 (ops from prev ph7) */          \
    _Pragma("unroll")                                                            \
    for (int mq = 0; mq < 4; ++mq) aF[mq][1] = RD_A(p, 0, mq, 1);                \
    _Pragma("unroll")                                                            \
    for (int nq = 0; nq < 2; ++nq) bL[nq][1] = RD_B(p, 0, nq, 1);                \
    MFMA_G(0, 0, 0, bL);                                                         \
    /* ph1: read bHk0(2) [for G3]; G2 */                                         \
    _Pragma("unroll")                                                            \
    for (int nq = 0; nq < 2; ++nq) bH[nq][0] = RD_B(p, 1, nq, 0);                \
    MFMA_G(0, 0, 1, bL);                                                         \
    SCHED0; __builtin_amdgcn_s_barrier(); SCHED0;                                \
    /* ph2: stage A-mh0; read bHk1(2) [for G4]; G3 */                            \
    if ((kt) + 2 < NT) { STAGE_A(p, 0, (kt) + 2); STAGE_A(p, 2, (kt) + 2); }     \
    _Pragma("unroll")                                                            \
    for (int nq = 0; nq < 2; ++nq) bH[nq][1] = RD_B(p, 1, nq, 1);                \
    MFMA_G(0, 1, 0, bH);                                                         \
    /* ph3: read aF1k0(4) into aF[*][0] (free after G3) [for G5]; G4 */          \
    _Pragma("unroll")                                                            \
    for (int mq = 0; mq < 4; ++mq) aF[mq][0] = RD_A(p, 1, mq, 0);                \
    MFMA_G(0, 1, 1, bH);                                                         \
    SCHED0; __builtin_amdgcn_s_barrier(); SCHED0;                                \
    /* ph4: stage B; read aF1k1(4) into aF[*][1] (free after G4) [for G6]; G5 */ \
    if ((kt) + 2 < NT) {                                                         \
        STAGE_B(p, 0, (kt) + 2); STAGE_B(p, 1, (kt) + 2);                        \
        STAGE_B(p, 2, (kt) + 2); STAGE_B(p, 3, (kt) + 2);                        \
    }                                                                            \
    _Pragma("unroll")                                                            \
    for (int mq = 0; mq < 4; ++mq) aF[mq][1] = RD_A(p, 1, mq, 1);                \
    MFMA_G(1, 1, 0, bH);                                                         \
    /* ph5: G6 */                                                                \
    MFMA_G(1, 1, 1, bH);                                                         \
    SCHED0; __builtin_amdgcn_s_barrier(); SCHED0;                                \
    /* ph6: stage A-mh1; G7 */                                                   \
    if ((kt) + 2 < NT) { STAGE_A(p, 1, (kt) + 2); STAGE_A(p, 3, (kt) + 2); }     \
    MFMA_G(1, 0, 0, bL);                                                         \
    /* ph7: vmcnt gate; cross-buffer reads for next tile's G1; G8 */             \
    if ((kt) + 2 < NT) { asm volatile("s_waitcnt vmcnt(8)" ::: "memory"); }      \
    else               { asm volatile("s_waitcnt vmcnt(0)" ::: "memory"); }      \
    SCHED0; __builtin_amdgcn_s_barrier(); SCHED0;                                \
    if ((kt) + 1 < NT) {                                                         \
        _Pragma("unroll")                                                        \
        for (int mq = 0; mq < 4; ++mq) aF[mq][0] = RD_A((p) ^ 1, 0, mq, 0);      \
        _Pragma("unroll")                                                        \
        for (int nq = 0; nq < 2; ++nq) bL[nq][0] = RD_B((p) ^ 1, 0, nq, 0);      \
    }                                                                            \
    MFMA_G(1, 0, 1, bL);                                                         \
} while (0)

__global__ __launch_bounds__(512, 1) void gemm_bin_kernel(const char* __restrict__ A,  // M x K i8
                                                          const char* __restrict__ B,  // N x K i8
                                                          const float* __restrict__ bias,
                                                          float* __restrict__ C) {
    // 128 KiB: A[2][4 blk][8 granules of 1024B], B same at +65536
    __shared__ __align__(16) unsigned char lds[131072];

    // T1: XCD-aware bijective swizzle (256 wgs, 256 % 8 == 0)
    int bid  = blockIdx.x;
    int swz  = (bid & 7) * 32 + (bid >> 3);
    int brow = (swz >> 4) << 8;
    int bcol = (swz & 15) << 8;

    int t    = threadIdx.x;
    int l    = t & 63;
    int wid  = t >> 6;
    int wr   = wid >> 2;   // 0..1  (M half)
    int wc   = wid & 3;    // 0..3  (N quarter)

    // staging: thread t -> granule slot; source pre-permuted to c-major granules
    int growI = ((t >> 7) << 4) + (t & 15);                     // row within 64-row block
    int gkI   = (((t >> 6) & 1) << 6) + (((t >> 4) & 3) << 4);  // k byte offset in BK=128

    const char* AbaseG = A + (size_t)(brow + growI) * K_DIM + gkI;
    const char* BbaseG = B + (size_t)(bcol + growI) * K_DIM + gkI;

    // fragment reads: granule-contiguous, base + lane*16
    const char* ldsc = (const char*)lds;
    int aB = wr * 16384 + (l << 4);
    int bB = wc * 8192  + (l << 4);

    i32x4 acc[8][4];
#pragma unroll
    for (int i = 0; i < 8; ++i)
#pragma unroll
        for (int j = 0; j < 4; ++j)
            acc[i][j] = (i32x4){0, 0, 0, 0};

    i32x4 aF[4][2], bL[2][2], bH[2][2];

    // prologue: stage tiles 0 (buf0) and 1 (buf1); drain so tile 0 landed;
    // pre-read G1 operands of tile 0 (plays the role of "prev ph7")
#pragma unroll
    for (int b = 0; b < 4; ++b) { STAGE_A(0, b, 0); }
#pragma unroll
    for (int b = 0; b < 4; ++b) { STAGE_B(0, b, 0); }
#pragma unroll
    for (int b = 0; b < 4; ++b) { STAGE_A(1, b, 1); }
#pragma unroll
    for (int b = 0; b < 4; ++b) { STAGE_B(1, b, 1); }
    asm volatile("s_waitcnt vmcnt(8)" ::: "memory");
    __builtin_amdgcn_s_barrier();
    SCHED0;
#pragma unroll
    for (int mq = 0; mq < 4; ++mq) aF[mq][0] = RD_A(0, 0, mq, 0);
#pragma unroll
    for (int nq = 0; nq < 2; ++nq) bL[nq][0] = RD_B(0, 0, nq, 0);

    for (int kt2 = 0; kt2 < NT; kt2 += 2) {
        TILE8(kt2, 0);
        TILE8(kt2 + 1, 1);
    }

    // epilogue: C/D layout col=lane&15, row=(lane>>4)*4+reg; dequant 1/32
    int klo  = l >> 4;
    int lrow = l & 15;
    int crow = brow + wr * 128 + klo * 4;
    int ccol = bcol + wc * 64 + lrow;
#pragma unroll
    for (int ni = 0; ni < 4; ++ni) {
        int col = ccol + (ni >> 1) * 32 + (ni & 1) * 16;
        float bv = bias[col];
#pragma unroll
        for (int mi = 0; mi < 8; ++mi) {
            int row = crow + (mi >> 2) * 64 + (mi & 3) * 16;
#pragma unroll
            for (int r = 0; r < 4; ++r)
                C[(size_t)(row + r) * N_DIM + col] =
                    (float)acc[mi][ni][r] * 0.03125f + bv;
        }
    }
}

extern "C" void kernel_launch(void* const* d_in, const int* in_sizes, int n_in,
                              void* d_out, int out_size, void* d_ws, size_t ws_size,
                              hipStream_t stream) {
    const float* x = (const float*)d_in[0];   // (4096, 4096) f32
    const float* W = (const float*)d_in[1];   // (4096, 4096) f32
    const float* b = (const float*)d_in[2];   // (4096,) f32
    float* out = (float*)d_out;               // (4096, 4096) f32

    char* xq  = (char*)d_ws;                              // 16 MB: x as i8 (M x K), scale 32
    char* WqT = (char*)d_ws + (size_t)M_DIM * K_DIM;      // 16 MB: sign(W) i8, N x K

    cvt_x_kernel<<<2048, 256, 0, stream>>>(x, xq, M_DIM * K_DIM / 16);
    sign_wt_kernel<<<dim3(N_DIM / 64, K_DIM / 64), dim3(64, 4), 0, stream>>>(W, WqT);
    gemm_bin_kernel<<<dim3(256), dim3(512), 0, stream>>>(xq, WqT, b, out);
}